// Round 2
// baseline (242.035 us; speedup 1.0000x reference)
//
#include <hip/hip_runtime.h>
#include <stdint.h>

typedef unsigned short u16;
typedef __attribute__((ext_vector_type(8))) short bf16x8;   // 8 bf16 in 4 VGPR
typedef __attribute__((ext_vector_type(4))) float f32x4;

#define NSEQ  2048
#define EMBED 1024
#define NHEAD 16
#define HDIM  64

// fp32 -> bf16, round-nearest-even
__device__ __forceinline__ u16 f2bf(float f) {
  uint32_t u = __builtin_bit_cast(uint32_t, f);
  u += 0x7fffu + ((u >> 16) & 1u);
  return (u16)(u >> 16);
}

// async global->LDS, 16B per lane. Dest must be wave-uniform base (+lane*16 implied).
__device__ __forceinline__ void gl_lds16(const void* g, void* l) {
  __builtin_amdgcn_global_load_lds(
      (const __attribute__((address_space(1))) void*)g,
      (__attribute__((address_space(3))) void*)l, 16, 0, 0);
}

// ---------------------------------------------------------------------------
// fp32 -> bf16 weight conversion (w_qkv: 3072x1024, w_out: 1024x1024)
// ---------------------------------------------------------------------------
struct alignas(8) us4 { u16 a, b, c, d; };

__global__ __launch_bounds__(256)
void convertw(const float* __restrict__ wq, const float* __restrict__ wo,
              u16* __restrict__ oq, u16* __restrict__ oo) {
  int idx = blockIdx.x * 256 + threadIdx.x;          // one float4 per thread
  const float* src;
  u16* dst;
  if (idx < 786432) { src = wq; dst = oq; }          // 3072*1024/4
  else { idx -= 786432; src = wo; dst = oo; }        // 1024*1024/4
  f32x4 v = ((const f32x4*)src)[idx];
  us4 r;
  r.a = f2bf(v[0]); r.b = f2bf(v[1]); r.c = f2bf(v[2]); r.d = f2bf(v[3]);
  ((us4*)dst)[idx] = r;
}

// ---------------------------------------------------------------------------
// x [B][C][N] fp32 -> xT [B][N][C] bf16   (LDS 32x33 tile transpose)
// ---------------------------------------------------------------------------
__global__ __launch_bounds__(256)
void transpose_x(const float* __restrict__ x, u16* __restrict__ xT) {
  __shared__ float tile[32][33];
  const int b = blockIdx.z;
  const int n0 = blockIdx.x * 32, c0 = blockIdx.y * 32;
  const int tx = threadIdx.x & 31, ty = threadIdx.x >> 5;   // ty 0..7
  const float* xb = x + (size_t)b * EMBED * NSEQ;
  #pragma unroll
  for (int k = 0; k < 4; ++k)
    tile[ty + k * 8][tx] = xb[(size_t)(c0 + ty + k * 8) * NSEQ + n0 + tx];
  __syncthreads();
  u16* xTb = xT + (size_t)b * NSEQ * EMBED;
  #pragma unroll
  for (int k = 0; k < 4; ++k)
    xTb[(size_t)(n0 + ty + k * 8) * EMBED + c0 + tx] = f2bf(tile[tx][ty + k * 8]);
}

// ---------------------------------------------------------------------------
// Generic C = A * B^T GEMM, A:[M][1024] bf16, B:[NC][1024] bf16, K=1024.
// 128x128 tile, BK=64, 4 waves (2x2), 16x16x32 bf16 MFMA, fp32 acc.
// LDS tiles [128][64] bf16 (128B rows) with byte^=( (row&7)<<4 ) swizzle,
// applied on the GLOBAL SOURCE side (global_load_lds dest stays linear).
// EPI 0: qkv projection (rows=n, cols=o; scatter into Q, K, Vt)
// EPI 1: output projection (rows=o, cols=n; store fp32 y)
// ---------------------------------------------------------------------------
template<int EPI>
__global__ __launch_bounds__(256, 2)
void gemm_bt(const u16* __restrict__ A, const u16* __restrict__ Bm,
             u16* __restrict__ o_q, u16* __restrict__ o_k, u16* __restrict__ o_vt,
             float* __restrict__ o_f)
{
  __shared__ u16 lA[128 * 64];
  __shared__ u16 lB[128 * 64];
  const int t  = threadIdx.x;
  const int w  = t >> 6;
  const int l  = t & 63;
  const int lr = l & 15, lh = l >> 4;
  const int wm = w >> 1, wn = w & 1;
  const int bz = blockIdx.z;
  const int m0 = blockIdx.x * 128;
  const int n0 = blockIdx.y * 128;

  const u16* Ab = A  + (EPI == 0 ? (size_t)bz * NSEQ * EMBED : (size_t)0);
  const u16* Bb = Bm + (EPI == 0 ? (size_t)0 : (size_t)bz * NSEQ * EMBED);

  f32x4 acc[4][4];
  #pragma unroll
  for (int i = 0; i < 4; ++i)
    #pragma unroll
    for (int j = 0; j < 4; ++j)
      acc[i][j] = (f32x4){0.f, 0.f, 0.f, 0.f};

  const int srow = t >> 3;      // 0..31 within an issue
  const int slot = t & 7;       // 16B slot within 128B row
  char* ldsA = (char*)lA + (w << 10);
  char* ldsB = (char*)lB + (w << 10);

  for (int k0 = 0; k0 < EMBED; k0 += 64) {
    __syncthreads();            // previous tile fully consumed
    #pragma unroll
    for (int i = 0; i < 4; ++i) {
      const int row = i * 32 + srow;
      const int sc  = ((slot * 16) ^ ((row & 7) << 4)) >> 1;  // swizzled src col (elems)
      gl_lds16(Ab + (size_t)(m0 + row) * EMBED + k0 + sc, ldsA + i * 4096);
      gl_lds16(Bb + (size_t)(n0 + row) * EMBED + k0 + sc, ldsB + i * 4096);
    }
    __syncthreads();            // staging visible (compiler drains vmcnt)
    #pragma unroll
    for (int kk = 0; kk < 2; ++kk) {
      bf16x8 af[4], bfr[4];
      #pragma unroll
      for (int mr = 0; mr < 4; ++mr) {
        const int row = wm * 64 + mr * 16 + lr;
        const int c2  = (kk * 64 + lh * 16) ^ ((row & 7) << 4);
        af[mr] = *(const bf16x8*)((const char*)lA + row * 128 + c2);
      }
      #pragma unroll
      for (int nc = 0; nc < 4; ++nc) {
        const int row = wn * 64 + nc * 16 + lr;
        const int c2  = (kk * 64 + lh * 16) ^ ((row & 7) << 4);
        bfr[nc] = *(const bf16x8*)((const char*)lB + row * 128 + c2);
      }
      #pragma unroll
      for (int mr = 0; mr < 4; ++mr)
        #pragma unroll
        for (int nc = 0; nc < 4; ++nc)
          acc[mr][nc] = __builtin_amdgcn_mfma_f32_16x16x32_bf16(
              af[mr], bfr[nc], acc[mr][nc], 0, 0, 0);
    }
  }

  if constexpr (EPI == 0) {
    // rows = n (sequence), cols = o in [0,3072): o = h*192 + {q|k|v}*64 + d
    #pragma unroll
    for (int mr = 0; mr < 4; ++mr) {
      #pragma unroll
      for (int nc = 0; nc < 4; ++nc) {
        const int o  = n0 + wn * 64 + nc * 16 + lr;
        const int h  = o / 192;
        const int rr = o - h * 192;
        const size_t bh = (size_t)bz * NHEAD + h;
        #pragma unroll
        for (int r = 0; r < 4; ++r) {
          const int n = m0 + wm * 64 + mr * 16 + lh * 4 + r;
          const u16 v = f2bf(acc[mr][nc][r]);
          if (rr < 64)       o_q [(bh * NSEQ + n) * HDIM + rr]         = v;
          else if (rr < 128) o_k [(bh * NSEQ + n) * HDIM + (rr - 64)]  = v;
          else               o_vt[(bh * HDIM + (rr - 128)) * NSEQ + n] = v;
        }
      }
    }
  } else {
    // rows = o (out channel), cols = n; y[b][o][n] fp32, coalesced over n
    #pragma unroll
    for (int mr = 0; mr < 4; ++mr)
      #pragma unroll
      for (int nc = 0; nc < 4; ++nc)
        #pragma unroll
        for (int r = 0; r < 4; ++r) {
          const int o = m0 + wm * 64 + mr * 16 + lh * 4 + r;
          const int n = n0 + wn * 64 + nc * 16 + lr;
          o_f[((size_t)bz * EMBED + o) * NSEQ + n] = acc[mr][nc][r];
        }
  }
}

// ---------------------------------------------------------------------------
// Flash attention: one block per (64-row q-tile, bh). 4 waves x 16 q-rows.
// Q,K: [bh][n][64] bf16 row-major; Vt: [bh][64][n] bf16.
// Online softmax in fp32 registers; P goes through per-wave LDS (acc-layout ->
// A-frag layout). Writes vals[b][n][c] bf16 (B^T operand of the out GEMM).
// ---------------------------------------------------------------------------
__global__ __launch_bounds__(256, 2)
void attn(const u16* __restrict__ Q, const u16* __restrict__ K,
          const u16* __restrict__ Vt, u16* __restrict__ vals)
{
  __shared__ u16 lQ[64 * 64], lK[64 * 64], lV[64 * 64];
  __shared__ u16 lP[4][16 * 64];
  const int t  = threadIdx.x;
  const int w  = t >> 6, l = t & 63;
  const int lr = l & 15, lh = l >> 4;
  const int q0 = blockIdx.x * 64;
  const int bh = blockIdx.y;
  const int b  = bh >> 4, h = bh & 15;
  const size_t qk0 = (size_t)bh * NSEQ * HDIM;
  const size_t vt0 = (size_t)bh * HDIM * NSEQ;
  const int srow = t >> 3, slot = t & 7;

  // stage Q tile once
  #pragma unroll
  for (int i = 0; i < 2; ++i) {
    const int row = i * 32 + srow;
    const int sc  = ((slot * 16) ^ ((row & 7) << 4)) >> 1;
    gl_lds16(Q + qk0 + (size_t)(q0 + row) * HDIM + sc,
             (char*)lQ + i * 4096 + (w << 10));
  }

  f32x4 accO[4];
  #pragma unroll
  for (int i = 0; i < 4; ++i) accO[i] = (f32x4){0.f, 0.f, 0.f, 0.f};
  float mrow[4], lrow[4];
  #pragma unroll
  for (int r = 0; r < 4; ++r) { mrow[r] = -1e30f; lrow[r] = 0.f; }
  bf16x8 qf[2];

  for (int j0 = 0; j0 < NSEQ; j0 += 64) {
    __syncthreads();                       // prev tile consumed (+Q drain on iter 0)
    #pragma unroll
    for (int i = 0; i < 2; ++i) {
      const int row = i * 32 + srow;
      const int sc  = ((slot * 16) ^ ((row & 7) << 4)) >> 1;
      gl_lds16(K  + qk0 + (size_t)(j0 + row) * HDIM + sc,
               (char*)lK + i * 4096 + (w << 10));
      gl_lds16(Vt + vt0 + (size_t)row * NSEQ + j0 + sc,
               (char*)lV + i * 4096 + (w << 10));
    }
    __syncthreads();
    if (j0 == 0) {                         // Q fragments, hoisted (stationary)
      const int qrow = w * 16 + lr;
      #pragma unroll
      for (int kk = 0; kk < 2; ++kk)
        qf[kk] = *(const bf16x8*)((const char*)lQ + qrow * 128 +
                                  ((kk * 64 + lh * 16) ^ ((qrow & 7) << 4)));
    }

    // S = Q K^T  (16 q-rows x 64 keys per wave)
    f32x4 accS[4];
    #pragma unroll
    for (int f = 0; f < 4; ++f) accS[f] = (f32x4){0.f, 0.f, 0.f, 0.f};
    #pragma unroll
    for (int kk = 0; kk < 2; ++kk)
      #pragma unroll
      for (int f = 0; f < 4; ++f) {
        const int row = f * 16 + lr;
        const int c2  = (kk * 64 + lh * 16) ^ ((row & 7) << 4);
        bf16x8 kf = *(const bf16x8*)((const char*)lK + row * 128 + c2);
        accS[f] = __builtin_amdgcn_mfma_f32_16x16x32_bf16(qf[kk], kf, accS[f], 0, 0, 0);
      }

    // online softmax: scale, tile row-max (16-lane butterfly), rescale, P, rowsum
    float tm[4];
    #pragma unroll
    for (int r = 0; r < 4; ++r) {
      #pragma unroll
      for (int f = 0; f < 4; ++f) accS[f][r] *= 0.125f;   // 1/sqrt(64)
      tm[r] = fmaxf(fmaxf(accS[0][r], accS[1][r]), fmaxf(accS[2][r], accS[3][r]));
    }
    #pragma unroll
    for (int s = 1; s < 16; s <<= 1)
      #pragma unroll
      for (int r = 0; r < 4; ++r)
        tm[r] = fmaxf(tm[r], __shfl_xor(tm[r], s, 64));
    float al[4];
    #pragma unroll
    for (int r = 0; r < 4; ++r) {
      const float nm = fmaxf(mrow[r], tm[r]);
      al[r] = __expf(mrow[r] - nm);
      mrow[r] = nm;
    }
    float prs[4] = {0.f, 0.f, 0.f, 0.f};
    #pragma unroll
    for (int f = 0; f < 4; ++f)
      #pragma unroll
      for (int r = 0; r < 4; ++r) {
        const float p = __expf(accS[f][r] - mrow[r]);
        prs[r] += p;
        const int prow = lh * 4 + r;                 // acc-layout row
        const int cb   = (f * 16 + lr) * 2;
        *(u16*)((char*)lP[w] + prow * 128 + (cb ^ ((prow & 7) << 4))) = f2bf(p);
      }
    #pragma unroll
    for (int s = 1; s < 16; s <<= 1)
      #pragma unroll
      for (int r = 0; r < 4; ++r)
        prs[r] += __shfl_xor(prs[r], s, 64);
    #pragma unroll
    for (int r = 0; r < 4; ++r) lrow[r] = lrow[r] * al[r] + prs[r];
    #pragma unroll
    for (int fd = 0; fd < 4; ++fd)
      #pragma unroll
      for (int r = 0; r < 4; ++r)
        accO[fd][r] *= al[r];

    // O += P V  (per-wave private lP: same-wave in-order DS, no barrier needed)
    #pragma unroll
    for (int kk = 0; kk < 2; ++kk) {
      const int c2p = (kk * 64 + lh * 16) ^ ((lr & 7) << 4);
      bf16x8 pf = *(const bf16x8*)((const char*)lP[w] + lr * 128 + c2p);
      #pragma unroll
      for (int fd = 0; fd < 4; ++fd) {
        const int row = fd * 16 + lr;
        const int c2  = (kk * 64 + lh * 16) ^ ((row & 7) << 4);
        bf16x8 vf = *(const bf16x8*)((const char*)lV + row * 128 + c2);
        accO[fd] = __builtin_amdgcn_mfma_f32_16x16x32_bf16(pf, vf, accO[fd], 0, 0, 0);
      }
    }
  }

  // epilogue: vals[b][n][h*64+d] = O / l
  #pragma unroll
  for (int fd = 0; fd < 4; ++fd)
    #pragma unroll
    for (int r = 0; r < 4; ++r) {
      const int n = q0 + w * 16 + lh * 4 + r;
      const int c = h * HDIM + fd * 16 + lr;
      vals[((size_t)b * NSEQ + n) * EMBED + c] = f2bf(accO[fd][r] / lrow[r]);
    }
}

// ---------------------------------------------------------------------------
extern "C" void kernel_launch(void* const* d_in, const int* in_sizes, int n_in,
                              void* d_out, int out_size, void* d_ws, size_t ws_size,
                              hipStream_t stream) {
  const float* x    = (const float*)d_in[0];
  const float* wqkv = (const float*)d_in[1];
  const float* wout = (const float*)d_in[2];
  float* y = (float*)d_out;
  char* ws = (char*)d_ws;

  // workspace layout (48 MB total)
  u16* b_wqkv = (u16*)(ws);                    // 3072*1024*2 = 6 MB
  u16* b_wout = (u16*)(ws + 6291456);          // 1024*1024*2 = 2 MB
  u16* b_xT   = (u16*)(ws + 8388608);          // 2*2048*1024*2 = 8 MB
  u16* b_Q    = (u16*)(ws + 16777216);         // [32][2048][64] = 8 MB
  u16* b_K    = (u16*)(ws + 25165824);         // 8 MB
  u16* b_Vt   = (u16*)(ws + 33554432);         // [32][64][2048] = 8 MB
  u16* b_vals = (u16*)(ws + 41943040);         // [2][2048][1024] = 8 MB

  convertw<<<4096, 256, 0, stream>>>(wqkv, wout, b_wqkv, b_wout);
  transpose_x<<<dim3(64, 32, 2), 256, 0, stream>>>(x, b_xT);
  // qkv: C[n][o] = xT[b] (2048x1024) * w_qkv^T (3072x1024)^T
  gemm_bt<0><<<dim3(16, 24, 2), 256, 0, stream>>>(b_xT, b_wqkv, b_Q, b_K, b_Vt, nullptr);
  attn<<<dim3(32, 32), 256, 0, stream>>>(b_Q, b_K, b_Vt, b_vals);
  // out: C[o][n] = w_out (1024x1024) * vals[b]^T (2048x1024)^T
  gemm_bt<1><<<dim3(8, 16, 2), 256, 0, stream>>>(b_wout, b_vals, nullptr, nullptr, nullptr, y);
}

// Round 4
// 221.104 us; speedup vs baseline: 1.0947x; 1.0947x over previous
//
#include <hip/hip_runtime.h>
#include <stdint.h>

typedef unsigned short u16;
typedef __attribute__((ext_vector_type(8))) short bf16x8;   // 8 bf16 in 4 VGPR
typedef __attribute__((ext_vector_type(4))) float f32x4;

#define NSEQ  2048
#define EMBED 1024
#define NHEAD 16
#define HDIM  64
// 1/sqrt(HDIM) * log2(e): S is computed in log2 domain so P = exp2(S - m)
#define QSCALE 0.1803368801111204f

// fp32 -> bf16, round-nearest-even
__device__ __forceinline__ u16 f2bf(float f) {
  uint32_t u = __builtin_bit_cast(uint32_t, f);
  u += 0x7fffu + ((u >> 16) & 1u);
  return (u16)(u >> 16);
}

// pack two fp32 -> two bf16 (RNE) in one u32 (low = a)
__device__ __forceinline__ uint32_t pk2(float a, float b) {
  return (uint32_t)f2bf(a) | ((uint32_t)f2bf(b) << 16);
}

// async global->LDS, 16B per lane. Dest must be wave-uniform base (+lane*16 implied).
__device__ __forceinline__ void gl_lds16(const void* g, void* l) {
  __builtin_amdgcn_global_load_lds(
      (const __attribute__((address_space(1))) void*)g,
      (__attribute__((address_space(3))) void*)l, 16, 0, 0);
}

// ---------------------------------------------------------------------------
// fp32 -> bf16 weight conversion (w_qkv: 3072x1024, w_out: 1024x1024)
// ---------------------------------------------------------------------------
struct alignas(8) us4 { u16 a, b, c, d; };

__global__ __launch_bounds__(256)
void convertw(const float* __restrict__ wq, const float* __restrict__ wo,
              u16* __restrict__ oq, u16* __restrict__ oo) {
  int idx = blockIdx.x * 256 + threadIdx.x;          // one float4 per thread
  const float* src;
  u16* dst;
  if (idx < 786432) { src = wq; dst = oq; }          // 3072*1024/4
  else { idx -= 786432; src = wo; dst = oo; }        // 1024*1024/4
  f32x4 v = ((const f32x4*)src)[idx];
  us4 r;
  r.a = f2bf(v[0]); r.b = f2bf(v[1]); r.c = f2bf(v[2]); r.d = f2bf(v[3]);
  ((us4*)dst)[idx] = r;
}

// ---------------------------------------------------------------------------
// x [B][C][N] fp32 -> xT [B][N][C] bf16   (LDS 32x33 tile transpose)
// ---------------------------------------------------------------------------
__global__ __launch_bounds__(256)
void transpose_x(const float* __restrict__ x, u16* __restrict__ xT) {
  __shared__ float tile[32][33];
  const int b = blockIdx.z;
  const int n0 = blockIdx.x * 32, c0 = blockIdx.y * 32;
  const int tx = threadIdx.x & 31, ty = threadIdx.x >> 5;   // ty 0..7
  const float* xb = x + (size_t)b * EMBED * NSEQ;
  #pragma unroll
  for (int k = 0; k < 4; ++k)
    tile[ty + k * 8][tx] = xb[(size_t)(c0 + ty + k * 8) * NSEQ + n0 + tx];
  __syncthreads();
  u16* xTb = xT + (size_t)b * NSEQ * EMBED;
  #pragma unroll
  for (int k = 0; k < 4; ++k)
    xTb[(size_t)(n0 + ty + k * 8) * EMBED + c0 + tx] = f2bf(tile[tx][ty + k * 8]);
}

// ---------------------------------------------------------------------------
// Generic C = A * B^T GEMM, A:[M][1024] bf16, B:[NC][1024] bf16, K=1024.
// 128x128 tile, BK=64, 4 waves (2x2), 16x16x32 bf16 MFMA, fp32 acc.
// LDS tiles [128][64] bf16 (128B rows) with byte^=( (row&7)<<4 ) swizzle,
// applied on the GLOBAL SOURCE side (global_load_lds dest stays linear).
// EPI 0: qkv projection (rows=n, cols=o; scatter into Q(pre-scaled), K, Vt)
// EPI 1: output projection (rows=o, cols=n; store fp32 y)
// ---------------------------------------------------------------------------
template<int EPI>
__global__ __launch_bounds__(256, 2)
void gemm_bt(const u16* __restrict__ A, const u16* __restrict__ Bm,
             u16* __restrict__ o_q, u16* __restrict__ o_k, u16* __restrict__ o_vt,
             float* __restrict__ o_f)
{
  __shared__ u16 lA[128 * 64];
  __shared__ u16 lB[128 * 64];
  const int t  = threadIdx.x;
  const int w  = t >> 6;
  const int l  = t & 63;
  const int lr = l & 15, lh = l >> 4;
  const int wm = w >> 1, wn = w & 1;
  const int bz = blockIdx.z;
  const int m0 = blockIdx.x * 128;
  const int n0 = blockIdx.y * 128;

  const u16* Ab = A  + (EPI == 0 ? (size_t)bz * NSEQ * EMBED : (size_t)0);
  const u16* Bb = Bm + (EPI == 0 ? (size_t)0 : (size_t)bz * NSEQ * EMBED);

  f32x4 acc[4][4];
  #pragma unroll
  for (int i = 0; i < 4; ++i)
    #pragma unroll
    for (int j = 0; j < 4; ++j)
      acc[i][j] = (f32x4){0.f, 0.f, 0.f, 0.f};

  const int srow = t >> 3;      // 0..31 within an issue
  const int slot = t & 7;       // 16B slot within 128B row
  char* ldsA = (char*)lA + (w << 10);
  char* ldsB = (char*)lB + (w << 10);

  for (int k0 = 0; k0 < EMBED; k0 += 64) {
    __syncthreads();            // previous tile fully consumed
    #pragma unroll
    for (int i = 0; i < 4; ++i) {
      const int row = i * 32 + srow;
      const int sc  = ((slot * 16) ^ ((row & 7) << 4)) >> 1;  // swizzled src col (elems)
      gl_lds16(Ab + (size_t)(m0 + row) * EMBED + k0 + sc, ldsA + i * 4096);
      gl_lds16(Bb + (size_t)(n0 + row) * EMBED + k0 + sc, ldsB + i * 4096);
    }
    __syncthreads();            // staging visible (compiler drains vmcnt)
    #pragma unroll
    for (int kk = 0; kk < 2; ++kk) {
      bf16x8 af[4], bfr[4];
      #pragma unroll
      for (int mr = 0; mr < 4; ++mr) {
        const int row = wm * 64 + mr * 16 + lr;
        const int c2  = (kk * 64 + lh * 16) ^ ((row & 7) << 4);
        af[mr] = *(const bf16x8*)((const char*)lA + row * 128 + c2);
      }
      #pragma unroll
      for (int nc = 0; nc < 4; ++nc) {
        const int row = wn * 64 + nc * 16 + lr;
        const int c2  = (kk * 64 + lh * 16) ^ ((row & 7) << 4);
        bfr[nc] = *(const bf16x8*)((const char*)lB + row * 128 + c2);
      }
      #pragma unroll
      for (int mr = 0; mr < 4; ++mr)
        #pragma unroll
        for (int nc = 0; nc < 4; ++nc)
          acc[mr][nc] = __builtin_amdgcn_mfma_f32_16x16x32_bf16(
              af[mr], bfr[nc], acc[mr][nc], 0, 0, 0);
    }
  }

  if constexpr (EPI == 0) {
    // rows = n (sequence), cols = o in [0,3072): o = h*192 + {q|k|v}*64 + d
    #pragma unroll
    for (int mr = 0; mr < 4; ++mr) {
      #pragma unroll
      for (int nc = 0; nc < 4; ++nc) {
        const int o  = n0 + wn * 64 + nc * 16 + lr;
        const int h  = o / 192;
        const int rr = o - h * 192;
        const size_t bh = (size_t)bz * NHEAD + h;
        #pragma unroll
        for (int r = 0; r < 4; ++r) {
          const int n = m0 + wm * 64 + mr * 16 + lh * 4 + r;
          if (rr < 64)       o_q [(bh * NSEQ + n) * HDIM + rr]         = f2bf(acc[mr][nc][r] * QSCALE);
          else if (rr < 128) o_k [(bh * NSEQ + n) * HDIM + (rr - 64)]  = f2bf(acc[mr][nc][r]);
          else               o_vt[(bh * HDIM + (rr - 128)) * NSEQ + n] = f2bf(acc[mr][nc][r]);
        }
      }
    }
  } else {
    // rows = o (out channel), cols = n; y[b][o][n] fp32, coalesced over n
    #pragma unroll
    for (int mr = 0; mr < 4; ++mr)
      #pragma unroll
      for (int nc = 0; nc < 4; ++nc)
        #pragma unroll
        for (int r = 0; r < 4; ++r) {
          const int o = m0 + wm * 64 + mr * 16 + lh * 4 + r;
          const int n = n0 + wn * 64 + nc * 16 + lr;
          o_f[((size_t)bz * EMBED + o) * NSEQ + n] = acc[mr][nc][r];
        }
  }
}

// ---------------------------------------------------------------------------
// Flash attention v2: swapped operands -> lane-diagonal softmax.
//   S^T = mfma(K, Q)  : lane owns q-row lr (16 keys in-register)
//   O^T = mfma(Vt, P^T): acc col = q-row lr -> scalar m/lsum/rescale per lane
// Q pre-scaled by 1/sqrt(64)*log2e; P = exp2(S - m).
// LDS 24 KB: lK, lV, lQP (Q tile on iter 0, then per-wave P buffers:
// wave w's P = rows w*16..w*16+15 == exactly wave w's Q rows; same-wave
// in-order DS makes the alias safe).
// ---------------------------------------------------------------------------
__global__ __launch_bounds__(256, 5)
void attn(const u16* __restrict__ Q, const u16* __restrict__ K,
          const u16* __restrict__ Vt, u16* __restrict__ vals)
{
  __shared__ u16 lK[64 * 64], lV[64 * 64], lQP[64 * 64];
  const int t  = threadIdx.x;
  const int w  = t >> 6, l = t & 63;
  const int lr = l & 15, lh = l >> 4;
  const int q0 = blockIdx.x * 64;
  const int bh = blockIdx.y;
  const int b  = bh >> 4, h = bh & 15;
  const size_t qk0 = (size_t)bh * NSEQ * HDIM;
  const size_t vt0 = (size_t)bh * HDIM * NSEQ;
  const int srow = t >> 3, slot = t & 7;
  const int swzr = (lr & 7) << 4;
  char* const pbase = (char*)lQP + (w << 11) + lr * 128;  // wave-private P row

  // stage Q tile once (into lQP)
  #pragma unroll
  for (int i = 0; i < 2; ++i) {
    const int row = i * 32 + srow;
    const int sc  = ((slot * 16) ^ ((row & 7) << 4)) >> 1;
    gl_lds16(Q + qk0 + (size_t)(q0 + row) * HDIM + sc,
             (char*)lQP + i * 4096 + (w << 10));
  }

  f32x4 accO[4];
  #pragma unroll
  for (int i = 0; i < 4; ++i) accO[i] = (f32x4){0.f, 0.f, 0.f, 0.f};
  float m = -1e30f, lsum = 0.f;
  bf16x8 qf[2];

  for (int j0 = 0; j0 < NSEQ; j0 += 64) {
    __syncthreads();                       // prev tile consumed (+Q drain on iter 0)
    #pragma unroll
    for (int i = 0; i < 2; ++i) {
      const int row = i * 32 + srow;
      const int sc  = ((slot * 16) ^ ((row & 7) << 4)) >> 1;
      gl_lds16(K  + qk0 + (size_t)(j0 + row) * HDIM + sc,
               (char*)lK + i * 4096 + (w << 10));
      gl_lds16(Vt + vt0 + (size_t)row * NSEQ + j0 + sc,
               (char*)lV + i * 4096 + (w << 10));
    }
    __syncthreads();
    if (j0 == 0) {                         // Q fragments, hoisted (stationary)
      const int qrow = w * 16 + lr;
      #pragma unroll
      for (int kk = 0; kk < 2; ++kk)
        qf[kk] = *(const bf16x8*)((const char*)lQP + qrow * 128 +
                                  ((kk * 64 + lh * 16) ^ ((qrow & 7) << 4)));
    }

    // S^T = K Q^T : accS[f] rows = keys f*16+lh*4+r, col = q-row lr
    f32x4 accS[4];
    #pragma unroll
    for (int f = 0; f < 4; ++f) accS[f] = (f32x4){0.f, 0.f, 0.f, 0.f};
    #pragma unroll
    for (int kk = 0; kk < 2; ++kk)
      #pragma unroll
      for (int f = 0; f < 4; ++f) {
        const int row = f * 16 + lr;
        const int c2  = (kk * 64 + lh * 16) ^ ((row & 7) << 4);
        bf16x8 kf = *(const bf16x8*)((const char*)lK + row * 128 + c2);
        accS[f] = __builtin_amdgcn_mfma_f32_16x16x32_bf16(kf, qf[kk], accS[f], 0, 0, 0);
      }

    // in-lane online softmax for q-row lr (16 keys/lane, reduce across lh only)
    float fm[4];
    #pragma unroll
    for (int f = 0; f < 4; ++f)
      fm[f] = fmaxf(fmaxf(accS[f][0], accS[f][1]), fmaxf(accS[f][2], accS[f][3]));
    float tm = fmaxf(fmaxf(fm[0], fm[1]), fmaxf(fm[2], fm[3]));
    tm = fmaxf(tm, __shfl_xor(tm, 16, 64));
    tm = fmaxf(tm, __shfl_xor(tm, 32, 64));
    const float nm = fmaxf(m, tm);
    const float al = exp2f(m - nm);
    m = nm;

    float psum = 0.f;
    #pragma unroll
    for (int f = 0; f < 4; ++f) {
      const float e0 = exp2f(accS[f][0] - m);
      const float e1 = exp2f(accS[f][1] - m);
      const float e2 = exp2f(accS[f][2] - m);
      const float e3 = exp2f(accS[f][3] - m);
      psum += (e0 + e1) + (e2 + e3);
      uint2 pw;
      pw.x = pk2(e0, e1);
      pw.y = pk2(e2, e3);
      // keys f*16+lh*4+0..3 -> byte col f*32+lh*8, row lr, swizzled
      *(uint2*)(pbase + ((f * 32 + lh * 8) ^ swzr)) = pw;
    }
    psum += __shfl_xor(psum, 16, 64);
    psum += __shfl_xor(psum, 32, 64);
    lsum = lsum * al + psum;
    #pragma unroll
    for (int fd = 0; fd < 4; ++fd)
      #pragma unroll
      for (int r = 0; r < 4; ++r)
        accO[fd][r] *= al;

    // O^T += V^T P^T : A = Vt rows (d), B = P^T cols (q) -- both from LDS.
    // Same-wave in-order DS: P writes above are visible to our own reads.
    #pragma unroll
    for (int kk = 0; kk < 2; ++kk) {
      bf16x8 pf = *(const bf16x8*)(pbase + ((kk * 64 + lh * 16) ^ swzr));
      #pragma unroll
      for (int fd = 0; fd < 4; ++fd) {
        const int row = fd * 16 + lr;
        const int c2  = (kk * 64 + lh * 16) ^ ((row & 7) << 4);
        bf16x8 vf = *(const bf16x8*)((const char*)lV + row * 128 + c2);
        accO[fd] = __builtin_amdgcn_mfma_f32_16x16x32_bf16(vf, pf, accO[fd], 0, 0, 0);
      }
    }
  }

  // epilogue: lane holds O^T[d = fd*16+lh*4+r][q = lr]; 4x 8B stores
  const float rl = 1.0f / lsum;
  const int n = q0 + w * 16 + lr;
  #pragma unroll
  for (int fd = 0; fd < 4; ++fd) {
    uint2 ow;
    ow.x = pk2(accO[fd][0] * rl, accO[fd][1] * rl);
    ow.y = pk2(accO[fd][2] * rl, accO[fd][3] * rl);
    const int c = h * HDIM + fd * 16 + lh * 4;
    *(uint2*)(vals + ((size_t)b * NSEQ + n) * EMBED + c) = ow;
  }
}

// ---------------------------------------------------------------------------
extern "C" void kernel_launch(void* const* d_in, const int* in_sizes, int n_in,
                              void* d_out, int out_size, void* d_ws, size_t ws_size,
                              hipStream_t stream) {
  const float* x    = (const float*)d_in[0];
  const float* wqkv = (const float*)d_in[1];
  const float* wout = (const float*)d_in[2];
  float* y = (float*)d_out;
  char* ws = (char*)d_ws;

  // workspace layout (48 MB total)
  u16* b_wqkv = (u16*)(ws);                    // 3072*1024*2 = 6 MB
  u16* b_wout = (u16*)(ws + 6291456);          // 1024*1024*2 = 2 MB
  u16* b_xT   = (u16*)(ws + 8388608);          // 2*2048*1024*2 = 8 MB
  u16* b_Q    = (u16*)(ws + 16777216);         // [32][2048][64] = 8 MB (pre-scaled)
  u16* b_K    = (u16*)(ws + 25165824);         // 8 MB
  u16* b_Vt   = (u16*)(ws + 33554432);         // [32][64][2048] = 8 MB
  u16* b_vals = (u16*)(ws + 41943040);         // [2][2048][1024] = 8 MB

  convertw<<<4096, 256, 0, stream>>>(wqkv, wout, b_wqkv, b_wout);
  transpose_x<<<dim3(64, 32, 2), 256, 0, stream>>>(x, b_xT);
  // qkv: C[n][o] = xT[b] (2048x1024) * w_qkv^T (3072x1024)^T
  gemm_bt<0><<<dim3(16, 24, 2), 256, 0, stream>>>(b_xT, b_wqkv, b_Q, b_K, b_Vt, nullptr);
  attn<<<dim3(32, 32), 256, 0, stream>>>(b_Q, b_K, b_Vt, b_vals);
  // out: C[o][n] = w_out (1024x1024) * vals[b]^T (2048x1024)^T
  gemm_bt<1><<<dim3(8, 16, 2), 256, 0, stream>>>(b_wout, b_vals, nullptr, nullptr, nullptr, y);
}

// Round 5
// 215.229 us; speedup vs baseline: 1.1245x; 1.0273x over previous
//
#include <hip/hip_runtime.h>
#include <stdint.h>

typedef unsigned short u16;
typedef __attribute__((ext_vector_type(8))) short bf16x8;   // 8 bf16 in 4 VGPR
typedef __attribute__((ext_vector_type(4))) float f32x4;

#define NSEQ  2048
#define EMBED 1024
#define NHEAD 16
#define HDIM  64
// 1/sqrt(HDIM) * log2(e): S is computed in log2 domain so P = exp2(S - m)
#define QSCALE 0.1803368801111204f

// fp32 -> bf16, round-nearest-even
__device__ __forceinline__ u16 f2bf(float f) {
  uint32_t u = __builtin_bit_cast(uint32_t, f);
  u += 0x7fffu + ((u >> 16) & 1u);
  return (u16)(u >> 16);
}

// pack two fp32 -> two bf16 (RNE) in one u32 (low = a): single VALU instr
__device__ __forceinline__ uint32_t cvtpk(float a, float b) {
  uint32_t r;
  asm("v_cvt_pk_bf16_f32 %0, %1, %2" : "=v"(r) : "v"(a), "v"(b));
  return r;
}

// async global->LDS, 16B per lane. Dest must be wave-uniform base (+lane*16 implied).
__device__ __forceinline__ void gl_lds16(const void* g, void* l) {
  __builtin_amdgcn_global_load_lds(
      (const __attribute__((address_space(1))) void*)g,
      (__attribute__((address_space(3))) void*)l, 16, 0, 0);
}

// ---------------------------------------------------------------------------
// fp32 -> bf16 weight conversion (w_qkv: 3072x1024, w_out: 1024x1024)
// ---------------------------------------------------------------------------
struct alignas(8) us4 { u16 a, b, c, d; };

__global__ __launch_bounds__(256)
void convertw(const float* __restrict__ wq, const float* __restrict__ wo,
              u16* __restrict__ oq, u16* __restrict__ oo) {
  int idx = blockIdx.x * 256 + threadIdx.x;          // one float4 per thread
  const float* src;
  u16* dst;
  if (idx < 786432) { src = wq; dst = oq; }          // 3072*1024/4
  else { idx -= 786432; src = wo; dst = oo; }        // 1024*1024/4
  f32x4 v = ((const f32x4*)src)[idx];
  us4 r;
  r.a = f2bf(v[0]); r.b = f2bf(v[1]); r.c = f2bf(v[2]); r.d = f2bf(v[3]);
  ((us4*)dst)[idx] = r;
}

// ---------------------------------------------------------------------------
// x [B][C][N] fp32 -> xT [B][N][C] bf16   (LDS 32x33 tile transpose)
// ---------------------------------------------------------------------------
__global__ __launch_bounds__(256)
void transpose_x(const float* __restrict__ x, u16* __restrict__ xT) {
  __shared__ float tile[32][33];
  const int b = blockIdx.z;
  const int n0 = blockIdx.x * 32, c0 = blockIdx.y * 32;
  const int tx = threadIdx.x & 31, ty = threadIdx.x >> 5;   // ty 0..7
  const float* xb = x + (size_t)b * EMBED * NSEQ;
  #pragma unroll
  for (int k = 0; k < 4; ++k)
    tile[ty + k * 8][tx] = xb[(size_t)(c0 + ty + k * 8) * NSEQ + n0 + tx];
  __syncthreads();
  u16* xTb = xT + (size_t)b * NSEQ * EMBED;
  #pragma unroll
  for (int k = 0; k < 4; ++k)
    xTb[(size_t)(n0 + ty + k * 8) * EMBED + c0 + tx] = f2bf(tile[tx][ty + k * 8]);
}

// ---------------------------------------------------------------------------
// Generic C = A * B^T GEMM, A:[M][1024] bf16, B:[NC][1024] bf16, K=1024.
// 128x128 tile, BK=64, 4 waves (2x2), 16x16x32 bf16 MFMA, fp32 acc.
// LDS tiles [128][64] bf16 (128B rows) with byte^=( (row&7)<<4 ) swizzle,
// applied on the GLOBAL SOURCE side (global_load_lds dest stays linear).
// EPI 0: qkv projection (rows=n, cols=o; scatter into Q(pre-scaled), K, Vt)
// EPI 1: output projection (rows=o, cols=n; store fp32 y)
// ---------------------------------------------------------------------------
template<int EPI>
__global__ __launch_bounds__(256, 2)
void gemm_bt(const u16* __restrict__ A, const u16* __restrict__ Bm,
             u16* __restrict__ o_q, u16* __restrict__ o_k, u16* __restrict__ o_vt,
             float* __restrict__ o_f)
{
  __shared__ u16 lA[128 * 64];
  __shared__ u16 lB[128 * 64];
  const int t  = threadIdx.x;
  const int w  = t >> 6;
  const int l  = t & 63;
  const int lr = l & 15, lh = l >> 4;
  const int wm = w >> 1, wn = w & 1;
  const int bz = blockIdx.z;
  const int m0 = blockIdx.x * 128;
  const int n0 = blockIdx.y * 128;

  const u16* Ab = A  + (EPI == 0 ? (size_t)bz * NSEQ * EMBED : (size_t)0);
  const u16* Bb = Bm + (EPI == 0 ? (size_t)0 : (size_t)bz * NSEQ * EMBED);

  f32x4 acc[4][4];
  #pragma unroll
  for (int i = 0; i < 4; ++i)
    #pragma unroll
    for (int j = 0; j < 4; ++j)
      acc[i][j] = (f32x4){0.f, 0.f, 0.f, 0.f};

  const int srow = t >> 3;      // 0..31 within an issue
  const int slot = t & 7;       // 16B slot within 128B row
  char* ldsA = (char*)lA + (w << 10);
  char* ldsB = (char*)lB + (w << 10);

  for (int k0 = 0; k0 < EMBED; k0 += 64) {
    __syncthreads();            // previous tile fully consumed
    #pragma unroll
    for (int i = 0; i < 4; ++i) {
      const int row = i * 32 + srow;
      const int sc  = ((slot * 16) ^ ((row & 7) << 4)) >> 1;  // swizzled src col (elems)
      gl_lds16(Ab + (size_t)(m0 + row) * EMBED + k0 + sc, ldsA + i * 4096);
      gl_lds16(Bb + (size_t)(n0 + row) * EMBED + k0 + sc, ldsB + i * 4096);
    }
    __syncthreads();            // staging visible (compiler drains vmcnt)
    #pragma unroll
    for (int kk = 0; kk < 2; ++kk) {
      bf16x8 af[4], bfr[4];
      #pragma unroll
      for (int mr = 0; mr < 4; ++mr) {
        const int row = wm * 64 + mr * 16 + lr;
        const int c2  = (kk * 64 + lh * 16) ^ ((row & 7) << 4);
        af[mr] = *(const bf16x8*)((const char*)lA + row * 128 + c2);
      }
      #pragma unroll
      for (int nc = 0; nc < 4; ++nc) {
        const int row = wn * 64 + nc * 16 + lr;
        const int c2  = (kk * 64 + lh * 16) ^ ((row & 7) << 4);
        bfr[nc] = *(const bf16x8*)((const char*)lB + row * 128 + c2);
      }
      #pragma unroll
      for (int mr = 0; mr < 4; ++mr)
        #pragma unroll
        for (int nc = 0; nc < 4; ++nc)
          acc[mr][nc] = __builtin_amdgcn_mfma_f32_16x16x32_bf16(
              af[mr], bfr[nc], acc[mr][nc], 0, 0, 0);
    }
  }

  if constexpr (EPI == 0) {
    // rows = n (sequence), cols = o in [0,3072): o = h*192 + {q|k|v}*64 + d
    #pragma unroll
    for (int mr = 0; mr < 4; ++mr) {
      #pragma unroll
      for (int nc = 0; nc < 4; ++nc) {
        const int o  = n0 + wn * 64 + nc * 16 + lr;
        const int h  = o / 192;
        const int rr = o - h * 192;
        const size_t bh = (size_t)bz * NHEAD + h;
        #pragma unroll
        for (int r = 0; r < 4; ++r) {
          const int n = m0 + wm * 64 + mr * 16 + lh * 4 + r;
          if (rr < 64)       o_q [(bh * NSEQ + n) * HDIM + rr]         = f2bf(acc[mr][nc][r] * QSCALE);
          else if (rr < 128) o_k [(bh * NSEQ + n) * HDIM + (rr - 64)]  = f2bf(acc[mr][nc][r]);
          else               o_vt[(bh * HDIM + (rr - 128)) * NSEQ + n] = f2bf(acc[mr][nc][r]);
        }
      }
    }
  } else {
    // rows = o (out channel), cols = n; y[b][o][n] fp32, coalesced over n
    #pragma unroll
    for (int mr = 0; mr < 4; ++mr)
      #pragma unroll
      for (int nc = 0; nc < 4; ++nc)
        #pragma unroll
        for (int r = 0; r < 4; ++r) {
          const int o = m0 + wm * 64 + mr * 16 + lh * 4 + r;
          const int n = n0 + wn * 64 + nc * 16 + lr;
          o_f[((size_t)bz * EMBED + o) * NSEQ + n] = acc[mr][nc][r];
        }
  }
}

// ---------------------------------------------------------------------------
// Flash attention v3: swapped operands (lane-diagonal softmax) + K/V
// double-buffer prefetch + XCD-aware bh placement + cvt_pk + defer-max.
//   S^T = mfma(K, Q)  : lane owns q-row lr (16 keys in-register)
//   O^T = mfma(Vt, P^T): acc col = q-row lr -> scalar m/lsum/rescale per lane
// Q pre-scaled by 1/sqrt(64)*log2e; P = exp2(S - m), m deferred (THR=8).
// LDS 40 KB: lK[2], lV[2] (dbuf), lQP (Q on iter 0, then per-wave P).
// Grid: flat 1024; decode so each XCD owns 4 whole heads (KV fits its L2).
// ---------------------------------------------------------------------------
__global__ __launch_bounds__(256, 4)
void attn(const u16* __restrict__ Q, const u16* __restrict__ K,
          const u16* __restrict__ Vt, u16* __restrict__ vals)
{
  __shared__ u16 lK[2][64 * 64], lV[2][64 * 64], lQP[64 * 64];
  const int t  = threadIdx.x;
  const int w  = t >> 6, l = t & 63;
  const int lr = l & 15, lh = l >> 4;
  // XCD-aware decode: xcd = bid&7 owns bh { xcd, xcd+8, xcd+16, xcd+24 }
  const int bid = blockIdx.x;
  const int s   = bid >> 3;                  // 0..127
  const int bh  = (bid & 7) + 8 * (s >> 5);  // 4 whole heads per XCD
  const int q0  = (s & 31) * 64;
  const int b  = bh >> 4, h = bh & 15;
  const size_t qk0 = (size_t)bh * NSEQ * HDIM;
  const size_t vt0 = (size_t)bh * HDIM * NSEQ;
  const int srow = t >> 3, slot = t & 7;
  const int swzr = (lr & 7) << 4;
  char* const pbase = (char*)lQP + (w << 11) + lr * 128;  // wave-private P row

  // prologue: stage Q tile + K/V tile 0 (buf 0)
  #pragma unroll
  for (int i = 0; i < 2; ++i) {
    const int row = i * 32 + srow;
    const int sc  = ((slot * 16) ^ ((row & 7) << 4)) >> 1;
    gl_lds16(Q + qk0 + (size_t)(q0 + row) * HDIM + sc,
             (char*)lQP + i * 4096 + (w << 10));
    gl_lds16(K + qk0 + (size_t)row * HDIM + sc,
             (char*)lK[0] + i * 4096 + (w << 10));
    gl_lds16(Vt + vt0 + (size_t)row * NSEQ + sc,
             (char*)lV[0] + i * 4096 + (w << 10));
  }
  __syncthreads();                           // drains vmcnt

  // Q fragments (stationary; own-wave rows only, P alias is same-wave safe)
  bf16x8 qf[2];
  {
    const int qrow = w * 16 + lr;
    #pragma unroll
    for (int kk = 0; kk < 2; ++kk)
      qf[kk] = *(const bf16x8*)((const char*)lQP + qrow * 128 +
                                ((kk * 64 + lh * 16) ^ ((qrow & 7) << 4)));
  }

  f32x4 accO[4];
  #pragma unroll
  for (int i = 0; i < 4; ++i) accO[i] = (f32x4){0.f, 0.f, 0.f, 0.f};
  float m = -1e30f, lsum = 0.f;
  int cur = 0;

  for (int j0 = 0; j0 < NSEQ; j0 += 64) {
    // prefetch next K/V tile into the other buffer (uniform guard)
    const int jn = j0 + 64;
    if (jn < NSEQ) {
      char* nk = (char*)lK[cur ^ 1];
      char* nv = (char*)lV[cur ^ 1];
      #pragma unroll
      for (int i = 0; i < 2; ++i) {
        const int row = i * 32 + srow;
        const int sc  = ((slot * 16) ^ ((row & 7) << 4)) >> 1;
        gl_lds16(K  + qk0 + (size_t)(jn + row) * HDIM + sc, nk + i * 4096 + (w << 10));
        gl_lds16(Vt + vt0 + (size_t)row * NSEQ + jn + sc,   nv + i * 4096 + (w << 10));
      }
    }
    const char* kb = (const char*)lK[cur];
    const char* vb = (const char*)lV[cur];

    // S^T = K Q^T : accS[f] rows = keys f*16+lh*4+r, col = q-row lr
    f32x4 accS[4];
    #pragma unroll
    for (int f = 0; f < 4; ++f) accS[f] = (f32x4){0.f, 0.f, 0.f, 0.f};
    __builtin_amdgcn_s_setprio(1);
    #pragma unroll
    for (int kk = 0; kk < 2; ++kk)
      #pragma unroll
      for (int f = 0; f < 4; ++f) {
        const int row = f * 16 + lr;
        const int c2  = (kk * 64 + lh * 16) ^ ((row & 7) << 4);
        bf16x8 kf = *(const bf16x8*)(kb + row * 128 + c2);
        accS[f] = __builtin_amdgcn_mfma_f32_16x16x32_bf16(kf, qf[kk], accS[f], 0, 0, 0);
      }
    __builtin_amdgcn_s_setprio(0);

    // tile max for q-row lr (in-lane 16 keys, then across lh)
    float fm[4];
    #pragma unroll
    for (int f = 0; f < 4; ++f)
      fm[f] = fmaxf(fmaxf(accS[f][0], accS[f][1]), fmaxf(accS[f][2], accS[f][3]));
    float tm = fmaxf(fmaxf(fm[0], fm[1]), fmaxf(fm[2], fm[3]));
    tm = fmaxf(tm, __shfl_xor(tm, 16, 64));
    tm = fmaxf(tm, __shfl_xor(tm, 32, 64));

    // defer-max (THR=8 in log2 domain): rescale only on big max growth
    if (tm > m + 8.f) {
      const float al = exp2f(m - tm);
      lsum *= al;
      #pragma unroll
      for (int fd = 0; fd < 4; ++fd)
        #pragma unroll
        for (int r = 0; r < 4; ++r)
          accO[fd][r] *= al;
      m = tm;
    }

    // P = exp2(S - m) (bounded by 2^8), pack via v_cvt_pk, wave-private LDS
    float psum = 0.f;
    #pragma unroll
    for (int f = 0; f < 4; ++f) {
      const float e0 = exp2f(accS[f][0] - m);
      const float e1 = exp2f(accS[f][1] - m);
      const float e2 = exp2f(accS[f][2] - m);
      const float e3 = exp2f(accS[f][3] - m);
      psum += (e0 + e1) + (e2 + e3);
      uint2 pw;
      pw.x = cvtpk(e0, e1);
      pw.y = cvtpk(e2, e3);
      // keys f*16+lh*4+0..3 -> byte col f*32+lh*8, row lr, swizzled
      *(uint2*)(pbase + ((f * 32 + lh * 8) ^ swzr)) = pw;
    }
    psum += __shfl_xor(psum, 16, 64);
    psum += __shfl_xor(psum, 32, 64);
    lsum += psum;

    // O^T += V^T P^T (same-wave in-order DS: P writes visible to own reads)
    __builtin_amdgcn_s_setprio(1);
    #pragma unroll
    for (int kk = 0; kk < 2; ++kk) {
      bf16x8 pf = *(const bf16x8*)(pbase + ((kk * 64 + lh * 16) ^ swzr));
      #pragma unroll
      for (int fd = 0; fd < 4; ++fd) {
        const int row = fd * 16 + lr;
        const int c2  = (kk * 64 + lh * 16) ^ ((row & 7) << 4);
        bf16x8 vf = *(const bf16x8*)(vb + row * 128 + c2);
        accO[fd] = __builtin_amdgcn_mfma_f32_16x16x32_bf16(vf, pf, accO[fd], 0, 0, 0);
      }
    }
    __builtin_amdgcn_s_setprio(0);

    __syncthreads();   // drains vmcnt (next tile staged) + all waves done with cur
    cur ^= 1;
  }

  // epilogue: lane holds O^T[d = fd*16+lh*4+r][q = lr]; 4x 8B stores
  const float rl = 1.0f / lsum;
  const int n = q0 + w * 16 + lr;
  #pragma unroll
  for (int fd = 0; fd < 4; ++fd) {
    uint2 ow;
    ow.x = cvtpk(accO[fd][0] * rl, accO[fd][1] * rl);
    ow.y = cvtpk(accO[fd][2] * rl, accO[fd][3] * rl);
    const int c = h * HDIM + fd * 16 + lh * 4;
    *(uint2*)(vals + ((size_t)b * NSEQ + n) * EMBED + c) = ow;
  }
}

// ---------------------------------------------------------------------------
extern "C" void kernel_launch(void* const* d_in, const int* in_sizes, int n_in,
                              void* d_out, int out_size, void* d_ws, size_t ws_size,
                              hipStream_t stream) {
  const float* x    = (const float*)d_in[0];
  const float* wqkv = (const float*)d_in[1];
  const float* wout = (const float*)d_in[2];
  float* y = (float*)d_out;
  char* ws = (char*)d_ws;

  // workspace layout (48 MB total)
  u16* b_wqkv = (u16*)(ws);                    // 3072*1024*2 = 6 MB
  u16* b_wout = (u16*)(ws + 6291456);          // 1024*1024*2 = 2 MB
  u16* b_xT   = (u16*)(ws + 8388608);          // 2*2048*1024*2 = 8 MB
  u16* b_Q    = (u16*)(ws + 16777216);         // [32][2048][64] = 8 MB (pre-scaled)
  u16* b_K    = (u16*)(ws + 25165824);         // 8 MB
  u16* b_Vt   = (u16*)(ws + 33554432);         // [32][64][2048] = 8 MB
  u16* b_vals = (u16*)(ws + 41943040);         // [2][2048][1024] = 8 MB

  convertw<<<4096, 256, 0, stream>>>(wqkv, wout, b_wqkv, b_wout);
  transpose_x<<<dim3(64, 32, 2), 256, 0, stream>>>(x, b_xT);
  // qkv: C[n][o] = xT[b] (2048x1024) * w_qkv^T (3072x1024)^T
  gemm_bt<0><<<dim3(16, 24, 2), 256, 0, stream>>>(b_xT, b_wqkv, b_Q, b_K, b_Vt, nullptr);
  attn<<<1024, 256, 0, stream>>>(b_Q, b_K, b_Vt, b_vals);
  // out: C[o][n] = w_out (1024x1024) * vals[b]^T (2048x1024)^T
  gemm_bt<1><<<dim3(8, 16, 2), 256, 0, stream>>>(b_wout, b_vals, nullptr, nullptr, nullptr, y);
}

// Round 6
// 200.160 us; speedup vs baseline: 1.2092x; 1.0753x over previous
//
#include <hip/hip_runtime.h>
#include <stdint.h>

typedef unsigned short u16;
typedef __attribute__((ext_vector_type(8))) short bf16x8;   // 8 bf16 in 4 VGPR
typedef __attribute__((ext_vector_type(4))) float f32x4;

#define NSEQ  2048
#define EMBED 1024
#define NHEAD 16
#define HDIM  64
// 1/sqrt(HDIM) * log2(e): S is computed in log2 domain so P = exp2(S - m)
#define QSCALE 0.1803368801111204f

// fp32 -> bf16, round-nearest-even
__device__ __forceinline__ u16 f2bf(float f) {
  uint32_t u = __builtin_bit_cast(uint32_t, f);
  u += 0x7fffu + ((u >> 16) & 1u);
  return (u16)(u >> 16);
}

// pack two fp32 -> two bf16 (RNE) in one u32 (low = a): single VALU instr
__device__ __forceinline__ uint32_t cvtpk(float a, float b) {
  uint32_t r;
  asm("v_cvt_pk_bf16_f32 %0, %1, %2" : "=v"(r) : "v"(a), "v"(b));
  return r;
}

// async global->LDS, 16B per lane. Dest must be wave-uniform base (+lane*16 implied).
__device__ __forceinline__ void gl_lds16(const void* g, void* l) {
  __builtin_amdgcn_global_load_lds(
      (const __attribute__((address_space(1))) void*)g,
      (__attribute__((address_space(3))) void*)l, 16, 0, 0);
}

// ---------------------------------------------------------------------------
// fp32 -> bf16 weight conversion (w_qkv: 3072x1024, w_out: 1024x1024)
// ---------------------------------------------------------------------------
struct alignas(8) us4 { u16 a, b, c, d; };

__global__ __launch_bounds__(256)
void convertw(const float* __restrict__ wq, const float* __restrict__ wo,
              u16* __restrict__ oq, u16* __restrict__ oo) {
  int idx = blockIdx.x * 256 + threadIdx.x;          // one float4 per thread
  const float* src;
  u16* dst;
  if (idx < 786432) { src = wq; dst = oq; }          // 3072*1024/4
  else { idx -= 786432; src = wo; dst = oo; }        // 1024*1024/4
  f32x4 v = ((const f32x4*)src)[idx];
  us4 r;
  r.a = f2bf(v[0]); r.b = f2bf(v[1]); r.c = f2bf(v[2]); r.d = f2bf(v[3]);
  ((us4*)dst)[idx] = r;
}

// ---------------------------------------------------------------------------
// x [B][C][N] fp32 -> xT [B][N][C] bf16   (LDS 32x33 tile transpose)
// ---------------------------------------------------------------------------
__global__ __launch_bounds__(256)
void transpose_x(const float* __restrict__ x, u16* __restrict__ xT) {
  __shared__ float tile[32][33];
  const int b = blockIdx.z;
  const int n0 = blockIdx.x * 32, c0 = blockIdx.y * 32;
  const int tx = threadIdx.x & 31, ty = threadIdx.x >> 5;   // ty 0..7
  const float* xb = x + (size_t)b * EMBED * NSEQ;
  #pragma unroll
  for (int k = 0; k < 4; ++k)
    tile[ty + k * 8][tx] = xb[(size_t)(c0 + ty + k * 8) * NSEQ + n0 + tx];
  __syncthreads();
  u16* xTb = xT + (size_t)b * NSEQ * EMBED;
  #pragma unroll
  for (int k = 0; k < 4; ++k)
    xTb[(size_t)(n0 + ty + k * 8) * EMBED + c0 + tx] = f2bf(tile[tx][ty + k * 8]);
}

// ---------------------------------------------------------------------------
// Generic C = A * B^T GEMM, A:[M][1024] bf16, B:[NC][1024] bf16, K=1024.
// Tile (MR*32) x 128, BK=64, 4 waves, 16x16x32 bf16 MFMA, fp32 acc.
// XCD-bijective swizzle of the (m,n) tile id: each XCD owns a contiguous
// range of n-panels -> B-panel re-reads are L2 hits.
// EPI 0 (MR=4): qkv projection (rows=n, cols=o; scatter Q(pre-scaled), K, Vt)
// EPI 1 (MR=2): output projection (rows=o, cols=n; store fp32 y), 2 blk/CU
// ---------------------------------------------------------------------------
template<int EPI, int MR>
__global__ __launch_bounds__(256, 2)
void gemm_bt(const u16* __restrict__ A, const u16* __restrict__ Bm,
             u16* __restrict__ o_q, u16* __restrict__ o_k, u16* __restrict__ o_vt,
             float* __restrict__ o_f)
{
  __shared__ u16 lA[MR * 32 * 64];
  __shared__ u16 lB[128 * 64];
  const int t  = threadIdx.x;
  const int w  = t >> 6;
  const int l  = t & 63;
  const int lr = l & 15, lh = l >> 4;
  const int wm = w >> 1, wn = w & 1;
  const int bz = blockIdx.z;
  // XCD-bijective remap: NT tiles/batch, NT%8==0
  const int NT  = (EPI == 0 ? 384 : 256);
  const int c   = blockIdx.x + 16 * blockIdx.y;
  const int swz = (c & 7) * (NT / 8) + (c >> 3);
  const int m0  = (swz & 15) * (MR * 32);
  const int n0  = (swz >> 4) * 128;

  const u16* Ab = A  + (EPI == 0 ? (size_t)bz * NSEQ * EMBED : (size_t)0);
  const u16* Bb = Bm + (EPI == 0 ? (size_t)0 : (size_t)bz * NSEQ * EMBED);

  f32x4 acc[MR][4];
  #pragma unroll
  for (int i = 0; i < MR; ++i)
    #pragma unroll
    for (int j = 0; j < 4; ++j)
      acc[i][j] = (f32x4){0.f, 0.f, 0.f, 0.f};

  const int srow = t >> 3;      // 0..31 within an issue
  const int slot = t & 7;       // 16B slot within 128B row
  char* ldsA = (char*)lA + (w << 10);
  char* ldsB = (char*)lB + (w << 10);

  for (int k0 = 0; k0 < EMBED; k0 += 64) {
    __syncthreads();            // previous tile fully consumed
    #pragma unroll
    for (int i = 0; i < MR; ++i) {
      const int row = i * 32 + srow;
      const int sc  = ((slot * 16) ^ ((row & 7) << 4)) >> 1;  // swizzled src col (elems)
      gl_lds16(Ab + (size_t)(m0 + row) * EMBED + k0 + sc, ldsA + i * 4096);
    }
    #pragma unroll
    for (int i = 0; i < 4; ++i) {
      const int row = i * 32 + srow;
      const int sc  = ((slot * 16) ^ ((row & 7) << 4)) >> 1;
      gl_lds16(Bb + (size_t)(n0 + row) * EMBED + k0 + sc, ldsB + i * 4096);
    }
    __syncthreads();            // staging visible (compiler drains vmcnt)
    #pragma unroll
    for (int kk = 0; kk < 2; ++kk) {
      bf16x8 af[MR], bfr[4];
      #pragma unroll
      for (int mr = 0; mr < MR; ++mr) {
        const int row = wm * (MR * 16) + mr * 16 + lr;
        const int c2  = (kk * 64 + lh * 16) ^ ((row & 7) << 4);
        af[mr] = *(const bf16x8*)((const char*)lA + row * 128 + c2);
      }
      #pragma unroll
      for (int nc = 0; nc < 4; ++nc) {
        const int row = wn * 64 + nc * 16 + lr;
        const int c2  = (kk * 64 + lh * 16) ^ ((row & 7) << 4);
        bfr[nc] = *(const bf16x8*)((const char*)lB + row * 128 + c2);
      }
      #pragma unroll
      for (int mr = 0; mr < MR; ++mr)
        #pragma unroll
        for (int nc = 0; nc < 4; ++nc)
          acc[mr][nc] = __builtin_amdgcn_mfma_f32_16x16x32_bf16(
              af[mr], bfr[nc], acc[mr][nc], 0, 0, 0);
    }
  }

  if constexpr (EPI == 0) {
    // rows = n (sequence), cols = o in [0,3072): o = h*192 + {q|k|v}*64 + d
    #pragma unroll
    for (int mr = 0; mr < MR; ++mr) {
      #pragma unroll
      for (int nc = 0; nc < 4; ++nc) {
        const int o  = n0 + wn * 64 + nc * 16 + lr;
        const int h  = o / 192;
        const int rr = o - h * 192;
        const size_t bh = (size_t)bz * NHEAD + h;
        #pragma unroll
        for (int r = 0; r < 4; ++r) {
          const int n = m0 + wm * (MR * 16) + mr * 16 + lh * 4 + r;
          if (rr < 64)       o_q [(bh * NSEQ + n) * HDIM + rr]         = f2bf(acc[mr][nc][r] * QSCALE);
          else if (rr < 128) o_k [(bh * NSEQ + n) * HDIM + (rr - 64)]  = f2bf(acc[mr][nc][r]);
          else               o_vt[(bh * HDIM + (rr - 128)) * NSEQ + n] = f2bf(acc[mr][nc][r]);
        }
      }
    }
  } else {
    // rows = o (out channel), cols = n; y[b][o][n] fp32, coalesced over n
    #pragma unroll
    for (int mr = 0; mr < MR; ++mr)
      #pragma unroll
      for (int nc = 0; nc < 4; ++nc)
        #pragma unroll
        for (int r = 0; r < 4; ++r) {
          const int o = m0 + wm * (MR * 16) + mr * 16 + lh * 4 + r;
          const int n = n0 + wn * 64 + nc * 16 + lr;
          o_f[((size_t)bz * EMBED + o) * NSEQ + n] = acc[mr][nc][r];
        }
  }
}

// ---------------------------------------------------------------------------
// Flash attention v4: swapped operands (lane-diagonal softmax), STATIC 2x
// unrolled K/V double-buffer (compile-time buffer indices -> loop-invariant
// LDS addresses), stage-issue after the buffer-freeing barrier, per-lane
// partial lsum (psum reduce deferred to epilogue), defer-max (THR=8),
// XCD-aware bh placement, cvt_pk packing.
// LDS 40 KB -> 4 blocks/CU; grid 1024 = 4 blocks/CU exactly.
// ---------------------------------------------------------------------------
__global__ __launch_bounds__(256, 4)
void attn(const u16* __restrict__ Q, const u16* __restrict__ K,
          const u16* __restrict__ Vt, u16* __restrict__ vals)
{
  __shared__ u16 lK[2][64 * 64], lV[2][64 * 64], lQP[64 * 64];
  const int t  = threadIdx.x;
  const int w  = t >> 6, l = t & 63;
  const int lr = l & 15, lh = l >> 4;
  // XCD-aware decode: xcd = bid&7 owns bh { xcd, xcd+8, xcd+16, xcd+24 }
  const int bid = blockIdx.x;
  const int s   = bid >> 3;                  // 0..127
  const int bh  = (bid & 7) + 8 * (s >> 5);  // 4 whole heads per XCD
  const int q0  = (s & 31) * 64;
  const int b  = bh >> 4, h = bh & 15;
  const size_t qk0 = (size_t)bh * NSEQ * HDIM;
  const size_t vt0 = (size_t)bh * HDIM * NSEQ;
  const int srow = t >> 3, slot = t & 7;
  const int swzr = (lr & 7) << 4;
  char* const pbase = (char*)lQP + (w << 11) + lr * 128;  // wave-private P row

// stage one 64-key K/V tile at J into buffers KB/VB (2 x 16B per thread each)
#define STAGE(J, KB, VB) do {                                                  \
    _Pragma("unroll")                                                          \
    for (int i_ = 0; i_ < 2; ++i_) {                                           \
      const int row_ = i_ * 32 + srow;                                         \
      const int sc_  = ((slot * 16) ^ ((row_ & 7) << 4)) >> 1;                 \
      gl_lds16(K  + qk0 + (size_t)((J) + row_) * HDIM + sc_,                   \
               (char*)(KB) + i_ * 4096 + (w << 10));                           \
      gl_lds16(Vt + vt0 + (size_t)row_ * NSEQ + (J) + sc_,                     \
               (char*)(VB) + i_ * 4096 + (w << 10));                           \
    }                                                                          \
  } while (0)

// process one 64-key tile from buffers KB/VB (S^T -> softmax -> O^T += PV)
#define ATILE(KB, VB) do {                                                     \
    f32x4 accS[4];                                                             \
    _Pragma("unroll")                                                          \
    for (int f_ = 0; f_ < 4; ++f_) accS[f_] = (f32x4){0.f, 0.f, 0.f, 0.f};     \
    __builtin_amdgcn_s_setprio(1);                                             \
    _Pragma("unroll")                                                          \
    for (int kk_ = 0; kk_ < 2; ++kk_)                                          \
      _Pragma("unroll")                                                        \
      for (int f_ = 0; f_ < 4; ++f_) {                                         \
        const int row_ = f_ * 16 + lr;                                         \
        const int c2_  = (kk_ * 64 + lh * 16) ^ swzr;                          \
        bf16x8 kf_ = *(const bf16x8*)((const char*)(KB) + row_ * 128 + c2_);   \
        accS[f_] = __builtin_amdgcn_mfma_f32_16x16x32_bf16(kf_, qf[kk_],       \
                                                           accS[f_], 0, 0, 0);\
      }                                                                        \
    __builtin_amdgcn_s_setprio(0);                                             \
    float fm0_ = fmaxf(fmaxf(accS[0][0], accS[0][1]), fmaxf(accS[0][2], accS[0][3])); \
    float fm1_ = fmaxf(fmaxf(accS[1][0], accS[1][1]), fmaxf(accS[1][2], accS[1][3])); \
    float fm2_ = fmaxf(fmaxf(accS[2][0], accS[2][1]), fmaxf(accS[2][2], accS[2][3])); \
    float fm3_ = fmaxf(fmaxf(accS[3][0], accS[3][1]), fmaxf(accS[3][2], accS[3][3])); \
    float tm_ = fmaxf(fmaxf(fm0_, fm1_), fmaxf(fm2_, fm3_));                   \
    tm_ = fmaxf(tm_, __shfl_xor(tm_, 16, 64));                                 \
    tm_ = fmaxf(tm_, __shfl_xor(tm_, 32, 64));                                 \
    if (tm_ > m + 8.f) {       /* defer-max: rescale only on big growth */     \
      const float al_ = exp2f(m - tm_);                                        \
      lsum *= al_;                                                             \
      _Pragma("unroll")                                                        \
      for (int fd_ = 0; fd_ < 4; ++fd_)                                        \
        _Pragma("unroll")                                                      \
        for (int r_ = 0; r_ < 4; ++r_) accO[fd_][r_] *= al_;                   \
      m = tm_;                                                                 \
    }                                                                          \
    _Pragma("unroll")                                                          \
    for (int f_ = 0; f_ < 4; ++f_) {                                           \
      const float e0_ = exp2f(accS[f_][0] - m);                                \
      const float e1_ = exp2f(accS[f_][1] - m);                                \
      const float e2_ = exp2f(accS[f_][2] - m);                                \
      const float e3_ = exp2f(accS[f_][3] - m);                                \
      lsum += (e0_ + e1_) + (e2_ + e3_);   /* per-lane partial; reduced once */\
      uint2 pw_;                                                               \
      pw_.x = cvtpk(e0_, e1_);                                                 \
      pw_.y = cvtpk(e2_, e3_);                                                 \
      *(uint2*)(pbase + ((f_ * 32 + lh * 8) ^ swzr)) = pw_;                    \
    }                                                                          \
    __builtin_amdgcn_s_setprio(1);                                             \
    _Pragma("unroll")                                                          \
    for (int kk_ = 0; kk_ < 2; ++kk_) {                                        \
      bf16x8 pf_ = *(const bf16x8*)(pbase + ((kk_ * 64 + lh * 16) ^ swzr));    \
      _Pragma("unroll")                                                        \
      for (int fd_ = 0; fd_ < 4; ++fd_) {                                      \
        const int row_ = fd_ * 16 + lr;                                        \
        const int c2_  = (kk_ * 64 + lh * 16) ^ swzr;                          \
        bf16x8 vf_ = *(const bf16x8*)((const char*)(VB) + row_ * 128 + c2_);   \
        accO[fd_] = __builtin_amdgcn_mfma_f32_16x16x32_bf16(vf_, pf_,          \
                                                            accO[fd_], 0, 0, 0);\
      }                                                                        \
    }                                                                          \
    __builtin_amdgcn_s_setprio(0);                                             \
  } while (0)

  // prologue: stage Q tile + K/V tiles 0 and 64
  #pragma unroll
  for (int i = 0; i < 2; ++i) {
    const int row = i * 32 + srow;
    const int sc  = ((slot * 16) ^ ((row & 7) << 4)) >> 1;
    gl_lds16(Q + qk0 + (size_t)(q0 + row) * HDIM + sc,
             (char*)lQP + i * 4096 + (w << 10));
  }
  STAGE(0, lK[0], lV[0]);
  STAGE(64, lK[1], lV[1]);
  __syncthreads();                           // drains vmcnt

  // Q fragments (stationary; own-wave rows only, P alias is same-wave safe)
  bf16x8 qf[2];
  {
    const int qrow = w * 16 + lr;
    #pragma unroll
    for (int kk = 0; kk < 2; ++kk)
      qf[kk] = *(const bf16x8*)((const char*)lQP + qrow * 128 +
                                ((kk * 64 + lh * 16) ^ ((qrow & 7) << 4)));
  }

  f32x4 accO[4];
  #pragma unroll
  for (int i = 0; i < 4; ++i) accO[i] = (f32x4){0.f, 0.f, 0.f, 0.f};
  float m = -1e30f, lsum = 0.f;

  // main loop: 15 bodies x 128 keys; static buffer indices; each staged tile
  // is in flight exactly one compute-phase before its draining barrier.
  for (int tt = 0; tt < 15; ++tt) {
    const int j0 = tt * 128;
    ATILE(lK[0], lV[0]);
    __syncthreads();             // all waves done buf0; drains stage(buf1)
    STAGE(j0 + 128, lK[0], lV[0]);
    ATILE(lK[1], lV[1]);
    __syncthreads();             // all waves done buf1; drains stage(buf0)
    STAGE(j0 + 192, lK[1], lV[1]);
  }
  // tail: tiles 1920 (buf0) and 1984 (buf1), no further staging
  ATILE(lK[0], lV[0]);
  __syncthreads();
  ATILE(lK[1], lV[1]);

  // epilogue: reduce per-lane lsum partials across lh, then scale+store O^T
  lsum += __shfl_xor(lsum, 16, 64);
  lsum += __shfl_xor(lsum, 32, 64);
  const float rl = 1.0f / lsum;
  const int n = q0 + w * 16 + lr;
  #pragma unroll
  for (int fd = 0; fd < 4; ++fd) {
    uint2 ow;
    ow.x = cvtpk(accO[fd][0] * rl, accO[fd][1] * rl);
    ow.y = cvtpk(accO[fd][2] * rl, accO[fd][3] * rl);
    const int c = h * HDIM + fd * 16 + lh * 4;
    *(uint2*)(vals + ((size_t)b * NSEQ + n) * EMBED + c) = ow;
  }
#undef STAGE
#undef ATILE
}

// ---------------------------------------------------------------------------
extern "C" void kernel_launch(void* const* d_in, const int* in_sizes, int n_in,
                              void* d_out, int out_size, void* d_ws, size_t ws_size,
                              hipStream_t stream) {
  const float* x    = (const float*)d_in[0];
  const float* wqkv = (const float*)d_in[1];
  const float* wout = (const float*)d_in[2];
  float* y = (float*)d_out;
  char* ws = (char*)d_ws;

  // workspace layout (48 MB total)
  u16* b_wqkv = (u16*)(ws);                    // 3072*1024*2 = 6 MB
  u16* b_wout = (u16*)(ws + 6291456);          // 1024*1024*2 = 2 MB
  u16* b_xT   = (u16*)(ws + 8388608);          // 2*2048*1024*2 = 8 MB
  u16* b_Q    = (u16*)(ws + 16777216);         // [32][2048][64] = 8 MB (pre-scaled)
  u16* b_K    = (u16*)(ws + 25165824);         // 8 MB
  u16* b_Vt   = (u16*)(ws + 33554432);         // [32][64][2048] = 8 MB
  u16* b_vals = (u16*)(ws + 41943040);         // [2][2048][1024] = 8 MB

  convertw<<<4096, 256, 0, stream>>>(wqkv, wout, b_wqkv, b_wout);
  transpose_x<<<dim3(64, 32, 2), 256, 0, stream>>>(x, b_xT);
  // qkv: C[n][o] = xT[b] (2048x1024) * w_qkv^T (3072x1024)^T
  gemm_bt<0, 4><<<dim3(16, 24, 2), 256, 0, stream>>>(b_xT, b_wqkv, b_Q, b_K, b_Vt, nullptr);
  attn<<<1024, 256, 0, stream>>>(b_Q, b_K, b_Vt, b_vals);
  // out: C[o][n] = w_out (1024x1024) * vals[b]^T (2048x1024)^T  (64x128 tiles)
  gemm_bt<1, 2><<<dim3(16, 16, 2), 256, 0, stream>>>(b_wout, b_vals, nullptr, nullptr, nullptr, y);
}